// Round 10
// baseline (247.622 us; speedup 1.0000x reference)
//
#include <hip/hip_runtime.h>
#include <cstdint>
#include <cstddef>

// DigitCapsule dynamic routing, fp32.
// x[256,1152,8], W[1152,10,16,8], out v[256,10,16].
// Design: lane = q*16 + d. d-reductions (logits, squash) are 16-lane
// xor-butterflies via ds_swizzle -> no barriers in capsV.
// vsum trick: logits at round r = votes . (v0+...+v_{r-1}).
// R10: FOUR b's per thread (R6's 2b -> -28% was the only proven lever; the
// binding is VMEM latency, and FMA-per-W-load is the only knob that moved
// it). Deferred-scale softmax: t[j] = exp(l[j])*vt[j] overwrites vt, then
// acc[j] += t[j]*rcp(S) after the j-loop -> l[] and vt[] never coexist,
// state ~184 VGPR. waves_per_eu(2,3) gives the allocator a 256-reg budget.
// CA=6 -> grid (192,4)=768 blocks = 3 blocks/CU supplies the 2-wave target.
constexpr int Bn = 256, In = 1152, Pn = 8, Jn = 10, Dn = 16;
constexpr int CA = 6, NCH = In / CA;  // 192 chunks

template <int MASK>
__device__ __forceinline__ float swzadd(float v) {
  const int s = __builtin_amdgcn_ds_swizzle(__float_as_int(v), MASK);
  return v + __int_as_float(s);
}

// Sum over the 16 lanes of each row (lane&15 = d); every lane gets the sum.
// ds_swizzle BitMode: offset = xor<<10 | or<<5 | and(0x1F). LDS pipe.
__device__ __forceinline__ float rowsum16(float v) {
  v = swzadd<0x041F>(v);  // xor 1
  v = swzadd<0x081F>(v);  // xor 2
  v = swzadd<0x101F>(v);  // xor 4
  v = swzadd<0x201F>(v);  // xor 8
  return v;
}

__device__ __forceinline__ float dot8(const float4 a0, const float4 a1,
                                      const float4 b0, const float4 b1) {
  float s = a0.x * b0.x;
  s = fmaf(a0.y, b0.y, s); s = fmaf(a0.z, b0.z, s); s = fmaf(a0.w, b0.w, s);
  s = fmaf(a1.x, b1.x, s); s = fmaf(a1.y, b1.y, s); s = fmaf(a1.z, b1.z, s);
  s = fmaf(a1.w, b1.w, s);
  return s;
}

// capsV: one routing round's weighted vote sum over an i-chunk, 4 b's/thread.
// thread: d = t&15, q = t>>4; b_k = blockIdx.y*64 + q + 16k, k=0..3.
// block = (chunk, b-group of 64). Per (i,j): one 32B W load -> four dots.
// MODE 1: per j: l_k = rowsum16(vt_k*vs_k); e=exp(l); vt_k *= e; S_k += e;
//         after j-loop: acc_k[j] += vt_k[j] * rcp(S_k).   (deferred scale)
// MODE 0: softmax of zero logits = 0.1 exactly -> raw vote sum * 0.1.
template <int MODE>
__global__ __launch_bounds__(256)
__attribute__((amdgpu_waves_per_eu(2, 3)))
void capsV(const float* __restrict__ x, const float* __restrict__ w,
           const float* __restrict__ vsumT, float* __restrict__ spart) {
  const int t = threadIdx.x;
  const int d = t & 15, q = t >> 4;
  const int ch = blockIdx.x;
  const int b0 = blockIdx.y * 64 + q;
  const int b1 = b0 + 16, b2 = b0 + 32, b3 = b0 + 48;

  float vs0[Jn], vs1[Jn], vs2[Jn], vs3[Jn];
  float acc0[Jn], acc1[Jn], acc2[Jn], acc3[Jn];
  #pragma unroll
  for (int j = 0; j < Jn; ++j) {
    acc0[j] = 0.f; acc1[j] = 0.f; acc2[j] = 0.f; acc3[j] = 0.f;
    if (MODE) {
      vs0[j] = vsumT[((size_t)j * Bn + b0) * Dn + d];
      vs1[j] = vsumT[((size_t)j * Bn + b1) * Dn + d];
      vs2[j] = vsumT[((size_t)j * Bn + b2) * Dn + d];
      vs3[j] = vsumT[((size_t)j * Bn + b3) * Dn + d];
    }
  }

  const int i0 = ch * CA;
  const float* xp0 = x + ((size_t)b0 * In + i0) * Pn;
  const float* xp1 = x + ((size_t)b1 * In + i0) * Pn;
  const float* xp2 = x + ((size_t)b2 * In + i0) * Pn;
  const float* xp3 = x + ((size_t)b3 * In + i0) * Pn;
  const float* wp = w + (((size_t)i0 * Jn) * Dn + d) * Pn;

  for (int ii = 0; ii < CA; ++ii) {
    const float4 xa0 = reinterpret_cast<const float4*>(xp0)[0];
    const float4 xa1 = reinterpret_cast<const float4*>(xp0)[1];
    const float4 xb0 = reinterpret_cast<const float4*>(xp1)[0];
    const float4 xb1 = reinterpret_cast<const float4*>(xp1)[1];
    const float4 xc0 = reinterpret_cast<const float4*>(xp2)[0];
    const float4 xc1 = reinterpret_cast<const float4*>(xp2)[1];
    const float4 xd0 = reinterpret_cast<const float4*>(xp3)[0];
    const float4 xd1 = reinterpret_cast<const float4*>(xp3)[1];

    float vt0[Jn], vt1[Jn], vt2[Jn], vt3[Jn];
    float sa = 0.f, sb = 0.f, sc = 0.f, sd = 0.f;

    #pragma unroll
    for (int j = 0; j < Jn; ++j) {
      const float4* wj =
          reinterpret_cast<const float4*>(wp + (size_t)j * (Dn * Pn));
      const float4 w0 = wj[0], w1 = wj[1];
      vt0[j] = dot8(w0, w1, xa0, xa1);
      vt1[j] = dot8(w0, w1, xb0, xb1);
      vt2[j] = dot8(w0, w1, xc0, xc1);
      vt3[j] = dot8(w0, w1, xd0, xd1);
      if (MODE) {
        // logits small (O(0.1)) -> no max-subtraction needed.
        const float e0 = __expf(rowsum16(vt0[j] * vs0[j]));
        const float e1 = __expf(rowsum16(vt1[j] * vs1[j]));
        const float e2 = __expf(rowsum16(vt2[j] * vs2[j]));
        const float e3 = __expf(rowsum16(vt3[j] * vs3[j]));
        vt0[j] *= e0; sa += e0;
        vt1[j] *= e1; sb += e1;
        vt2[j] *= e2; sc += e2;
        vt3[j] *= e3; sd += e3;
      }
    }

    if (MODE) {
      const float ia = __builtin_amdgcn_rcpf(sa);
      const float ib = __builtin_amdgcn_rcpf(sb);
      const float ic = __builtin_amdgcn_rcpf(sc);
      const float id = __builtin_amdgcn_rcpf(sd);
      #pragma unroll
      for (int j = 0; j < Jn; ++j) {
        acc0[j] = fmaf(vt0[j], ia, acc0[j]);
        acc1[j] = fmaf(vt1[j], ib, acc1[j]);
        acc2[j] = fmaf(vt2[j], ic, acc2[j]);
        acc3[j] = fmaf(vt3[j], id, acc3[j]);
      }
    } else {
      #pragma unroll
      for (int j = 0; j < Jn; ++j) {
        acc0[j] += vt0[j]; acc1[j] += vt1[j];
        acc2[j] += vt2[j]; acc3[j] += vt3[j];
      }
    }

    xp0 += Pn; xp1 += Pn; xp2 += Pn; xp3 += Pn;
    wp += (size_t)Jn * Dn * Pn;
  }

  const float cs = MODE ? 1.f : 0.1f;
  #pragma unroll
  for (int j = 0; j < Jn; ++j) {
    float* sp = spart + (((size_t)ch * Jn + j) * Bn) * Dn + d;
    sp[(size_t)b0 * Dn] = acc0[j] * cs;
    sp[(size_t)b1 * Dn] = acc1[j] * cs;
    sp[(size_t)b2 * Dn] = acc2[j] * cs;
    sp[(size_t)b3 * Dn] = acc3[j] * cs;
  }
}

// capsF: reduce 192 chunk-partials, squash. 1024 threads: 4 chunk-groups
// (cg = t>>8) each privately sum 48 chunks; LDS combine across cg; squash
// norm via rowsum16 in the t<256 tail. block = (j, b-group of 16).
// MODE 0: vsumT = v ; MODE 1: vsumT += v ; MODE 2: out[b][j][d] = v.
template <int MODE>
__global__ __launch_bounds__(1024) void capsF(
    const float* __restrict__ spart, float* __restrict__ vsumT,
    float* __restrict__ out) {
  __shared__ float red[4][16][16];
  const int t = threadIdx.x;
  const int cg = t >> 8, r = t & 255, g = r >> 4, d = r & 15;
  const int j = blockIdx.x, b = blockIdx.y * 16 + g;

  const size_t cstride = (size_t)Jn * Bn * Dn;  // one chunk, in floats
  const size_t cstep = 4 * cstride;             // stride between my chunks
  const float* sp = spart + (((size_t)cg * Jn + j) * Bn + b) * Dn + d;
  float s0 = 0.f, s1 = 0.f;
  #pragma unroll 4
  for (int k = 0; k < NCH / 4; k += 2) {
    s0 += sp[0];
    s1 += sp[cstep];
    sp += 2 * cstep;
  }
  red[cg][g][d] = s0 + s1;
  __syncthreads();
  if (t < 256) {
    const float z = red[0][g][d] + red[1][g][d] + red[2][g][d] + red[3][g][d];
    const float n2 = rowsum16(z * z);
    const float sc = n2 / (1.f + n2) / sqrtf(n2 + 1e-7f);
    const float v = z * sc;
    if (MODE == 2) {
      out[((size_t)b * Jn + j) * Dn + d] = v;
    } else if (MODE == 1) {
      vsumT[((size_t)j * Bn + b) * Dn + d] += v;
    } else {
      vsumT[((size_t)j * Bn + b) * Dn + d] = v;
    }
  }
}

extern "C" void kernel_launch(void* const* d_in, const int* in_sizes, int n_in,
                              void* d_out, int out_size, void* d_ws, size_t ws_size,
                              hipStream_t stream) {
  const float* x = (const float*)d_in[0];  // [256,1152,8]
  const float* w = (const float*)d_in[1];  // [1152,10,16,8]
  float* vsumT = (float*)d_ws;                      // [J][B][D]   0.16 MB
  float* spart = vsumT + (size_t)Jn * Bn * Dn;      // [NCH][J][B][D] 31.5 MB
  float* out = (float*)d_out;                       // [256,10,16]

  const dim3 gV(NCH, Bn / 64), gF(Jn, Bn / 16);

  capsV<0><<<gV, 256, 0, stream>>>(x, w, nullptr, spart);
  capsF<0><<<gF, 1024, 0, stream>>>(spart, vsumT, out);   // vsum = v0

  capsV<1><<<gV, 256, 0, stream>>>(x, w, vsumT, spart);   // round 1
  capsF<1><<<gF, 1024, 0, stream>>>(spart, vsumT, out);   // vsum += v1

  capsV<1><<<gV, 256, 0, stream>>>(x, w, vsumT, spart);   // round 2
  capsF<2><<<gF, 1024, 0, stream>>>(spart, vsumT, out);   // out = v2
}

// Round 11
// 169.508 us; speedup vs baseline: 1.4608x; 1.4608x over previous
//
#include <hip/hip_runtime.h>
#include <cstdint>
#include <cstddef>

// DigitCapsule dynamic routing, fp32.
// x[256,1152,8], W[1152,10,16,8], out v[256,10,16].
// Design: lane = q*16 + d. d-reductions (logits, squash) are 16-lane
// xor-butterflies via ds_swizzle. vsum trick: logits at round r =
// votes . (v0+...+v_{r-1}).
// R11: W chunk staged in LDS once per block (40KB, CA=8). Six rounds showed
// the backend keeps <=~12 global loads in flight per wave no matter what
// (VGPR ledger: 52..68 -> 58-65us, 84 -> 43.9us); W moves to the LDS
// latency class (~120cy, lgkmcnt-batched well by the compiler) and the 4
// waves/block stop redundantly re-fetching identical W through VMEM.
// Inner loop/softmax/geometry otherwise = R6 proven point (2b/thread,
// scalar fp32, waves_per_eu(3,4)).
constexpr int Bn = 256, In = 1152, Pn = 8, Jn = 10, Dn = 16;
constexpr int CA = 8, NCH = In / CA;  // 144 chunks

template <int MASK>
__device__ __forceinline__ float swzadd(float v) {
  const int s = __builtin_amdgcn_ds_swizzle(__float_as_int(v), MASK);
  return v + __int_as_float(s);
}

// Sum over the 16 lanes of each row (lane&15 = d); every lane gets the sum.
// ds_swizzle BitMode: offset = xor<<10 | or<<5 | and(0x1F). LDS pipe,
// does not touch LDS storage (pure lane permute).
__device__ __forceinline__ float rowsum16(float v) {
  v = swzadd<0x041F>(v);  // xor 1
  v = swzadd<0x081F>(v);  // xor 2
  v = swzadd<0x101F>(v);  // xor 4
  v = swzadd<0x201F>(v);  // xor 8
  return v;
}

__device__ __forceinline__ float dot8(const float4 a0, const float4 a1,
                                      const float4 b0, const float4 b1) {
  float s = a0.x * b0.x;
  s = fmaf(a0.y, b0.y, s); s = fmaf(a0.z, b0.z, s); s = fmaf(a0.w, b0.w, s);
  s = fmaf(a1.x, b1.x, s); s = fmaf(a1.y, b1.y, s); s = fmaf(a1.z, b1.z, s);
  s = fmaf(a1.w, b1.w, s);
  return s;
}

// capsV: one routing round's weighted vote sum over an i-chunk, 2 b's/thread.
// thread: d = t&15, q = t>>4; b0 = blockIdx.y*32 + q, b1 = b0 + 16.
// block = (chunk, b-group of 32).
// LDS: W chunk as 16B units, unit l = ((i_l*Jn + j)*2 + h)*16 + d
//   (d-transposed so lane d's b128 read spans 256B -> 2-way bank alias,
//    free; lane groups q=1..3 read identical addrs -> broadcast).
// Staging: thread reads global unit g = t + 256k (fully coalesced),
//   scatters to l(g): h=g&1, d=(g>>1)&15, ij=g>>5. One barrier, no reuse
//   hazards (chunk staged once per block).
// MODE 0: softmax of zero logits = 0.1 exactly -> raw vote sum * 0.1.
template <int MODE>
__global__ __launch_bounds__(256)
__attribute__((amdgpu_waves_per_eu(3, 4)))
void capsV(const float* __restrict__ x, const float* __restrict__ w,
           const float* __restrict__ vsumT, float* __restrict__ spart) {
  __shared__ float4 wlds[CA * Jn * 2 * 16];  // 40 KB
  const int t = threadIdx.x;
  const int d = t & 15, q = t >> 4;
  const int ch = blockIdx.x;
  const int b0 = blockIdx.y * 32 + q, b1 = b0 + 16;
  const int i0 = ch * CA;

  // ---- stage W chunk into LDS (coalesced global, permuted ds_write) ----
  const float4* wg =
      reinterpret_cast<const float4*>(w + (size_t)i0 * (Jn * Dn * Pn));
  #pragma unroll
  for (int k = 0; k < (CA * Jn * 2 * 16) / 256; ++k) {
    const int g = t + k * 256;
    const int h = g & 1, dd = (g >> 1) & 15, ij = g >> 5;
    wlds[(ij * 2 + h) * 16 + dd] = wg[g];
  }

  float vs0[Jn], vs1[Jn], acc0[Jn], acc1[Jn];
  #pragma unroll
  for (int j = 0; j < Jn; ++j) {
    acc0[j] = 0.f; acc1[j] = 0.f;
    if (MODE) {
      vs0[j] = vsumT[((size_t)j * Bn + b0) * Dn + d];
      vs1[j] = vsumT[((size_t)j * Bn + b1) * Dn + d];
    }
  }

  __syncthreads();  // staged W visible to all waves

  const float* xp0 = x + ((size_t)b0 * In + i0) * Pn;
  const float* xp1 = x + ((size_t)b1 * In + i0) * Pn;

  for (int ii = 0; ii < CA; ++ii) {
    const float4 xa0 = reinterpret_cast<const float4*>(xp0)[0];
    const float4 xa1 = reinterpret_cast<const float4*>(xp0)[1];
    const float4 xb0 = reinterpret_cast<const float4*>(xp1)[0];
    const float4 xb1 = reinterpret_cast<const float4*>(xp1)[1];

    float vt0[Jn], vt1[Jn];
    #pragma unroll
    for (int j = 0; j < Jn; ++j) {
      const float4* wrow = &wlds[((ii * Jn + j) * 2) * 16 + d];
      const float4 w0 = wrow[0];   // h=0
      const float4 w1 = wrow[16];  // h=1
      vt0[j] = dot8(w0, w1, xa0, xa1);
      vt1[j] = dot8(w0, w1, xb0, xb1);
    }

    if (MODE) {
      float l0[Jn], l1[Jn];
      #pragma unroll
      for (int j = 0; j < Jn; ++j) {
        l0[j] = rowsum16(vt0[j] * vs0[j]);
        l1[j] = rowsum16(vt1[j] * vs1[j]);
      }
      // softmax over j; logits are O(0.1) so no max-subtraction needed.
      float sa = 0.f, sb = 0.f;
      #pragma unroll
      for (int j = 0; j < Jn; ++j) {
        l0[j] = __expf(l0[j]); sa += l0[j];
        l1[j] = __expf(l1[j]); sb += l1[j];
      }
      const float ia = __builtin_amdgcn_rcpf(sa);
      const float ib = __builtin_amdgcn_rcpf(sb);
      #pragma unroll
      for (int j = 0; j < Jn; ++j) {
        acc0[j] = fmaf(l0[j] * ia, vt0[j], acc0[j]);
        acc1[j] = fmaf(l1[j] * ib, vt1[j], acc1[j]);
      }
    } else {
      #pragma unroll
      for (int j = 0; j < Jn; ++j) { acc0[j] += vt0[j]; acc1[j] += vt1[j]; }
    }

    xp0 += Pn;
    xp1 += Pn;
  }

  const float cs = MODE ? 1.f : 0.1f;
  #pragma unroll
  for (int j = 0; j < Jn; ++j) {
    spart[(((size_t)ch * Jn + j) * Bn + b0) * Dn + d] = acc0[j] * cs;
    spart[(((size_t)ch * Jn + j) * Bn + b1) * Dn + d] = acc1[j] * cs;
  }
}

// capsF: reduce 144 chunk-partials, squash. 1024 threads: 4 chunk-groups
// (cg = t>>8) each privately sum 36 chunks; LDS combine across cg; squash
// norm via rowsum16 in the t<256 tail. block = (j, b-group of 16).
// MODE 0: vsumT = v ; MODE 1: vsumT += v ; MODE 2: out[b][j][d] = v.
template <int MODE>
__global__ __launch_bounds__(1024) void capsF(
    const float* __restrict__ spart, float* __restrict__ vsumT,
    float* __restrict__ out) {
  __shared__ float red[4][16][16];
  const int t = threadIdx.x;
  const int cg = t >> 8, r = t & 255, g = r >> 4, d = r & 15;
  const int j = blockIdx.x, b = blockIdx.y * 16 + g;

  const size_t cstride = (size_t)Jn * Bn * Dn;  // one chunk, in floats
  const size_t cstep = 4 * cstride;             // stride between my chunks
  const float* sp = spart + (((size_t)cg * Jn + j) * Bn + b) * Dn + d;
  float s0 = 0.f, s1 = 0.f;
  #pragma unroll 4
  for (int k = 0; k < NCH / 4; k += 2) {
    s0 += sp[0];
    s1 += sp[cstep];
    sp += 2 * cstep;
  }
  red[cg][g][d] = s0 + s1;
  __syncthreads();
  if (t < 256) {
    const float z = red[0][g][d] + red[1][g][d] + red[2][g][d] + red[3][g][d];
    const float n2 = rowsum16(z * z);
    const float sc = n2 / (1.f + n2) / sqrtf(n2 + 1e-7f);
    const float v = z * sc;
    if (MODE == 2) {
      out[((size_t)b * Jn + j) * Dn + d] = v;
    } else if (MODE == 1) {
      vsumT[((size_t)j * Bn + b) * Dn + d] += v;
    } else {
      vsumT[((size_t)j * Bn + b) * Dn + d] = v;
    }
  }
}

extern "C" void kernel_launch(void* const* d_in, const int* in_sizes, int n_in,
                              void* d_out, int out_size, void* d_ws, size_t ws_size,
                              hipStream_t stream) {
  const float* x = (const float*)d_in[0];  // [256,1152,8]
  const float* w = (const float*)d_in[1];  // [1152,10,16,8]
  float* vsumT = (float*)d_ws;                      // [J][B][D]   0.16 MB
  float* spart = vsumT + (size_t)Jn * Bn * Dn;      // [NCH][J][B][D] 23.6 MB
  float* out = (float*)d_out;                       // [256,10,16]

  const dim3 gV(NCH, Bn / 32), gF(Jn, Bn / 16);

  capsV<0><<<gV, 256, 0, stream>>>(x, w, nullptr, spart);
  capsF<0><<<gF, 1024, 0, stream>>>(spart, vsumT, out);   // vsum = v0

  capsV<1><<<gV, 256, 0, stream>>>(x, w, vsumT, spart);   // round 1
  capsF<1><<<gF, 1024, 0, stream>>>(spart, vsumT, out);   // vsum += v1

  capsV<1><<<gV, 256, 0, stream>>>(x, w, vsumT, spart);   // round 2
  capsF<2><<<gF, 1024, 0, stream>>>(spart, vsumT, out);   // out = v2
}